// Round 1
// baseline (2501.161 us; speedup 1.0000x reference)
//
#include <hip/hip_runtime.h>
#include <hip/hip_bf16.h>

// Problem constants
#define BB 32
#define CC 128
#define OO 128
#define HH 56
#define WW 56
#define KK 4
#define HW 3136           // 56*56
#define WPLANE 147456     // OO*CC*9, per-k weight plane stride
#define EPSV 1e-5f

// ---------------- pooled = mean over H,W per (b,c) ----------------
__global__ void pool_kernel(const float* __restrict__ x, float* __restrict__ pooled) {
    int bc = blockIdx.x;                       // b*CC + c
    const float* p = x + (size_t)bc * HW;
    float s = 0.f;
    for (int e = threadIdx.x; e < HW; e += 256) s += p[e];
    for (int off = 32; off > 0; off >>= 1) s += __shfl_down(s, off, 64);
    __shared__ float red[4];
    int wid = threadIdx.x >> 6, lane = threadIdx.x & 63;
    if (lane == 0) red[wid] = s;
    __syncthreads();
    if (threadIdx.x == 0)
        pooled[bc] = (red[0] + red[1] + red[2] + red[3]) * (1.0f / HW);
}

// ---------------- attention MLP + softmax (one thread per sample) ----------------
__global__ void attn_kernel(const float* __restrict__ pooled,
                            const float* __restrict__ fc1_w, const float* __restrict__ fc1_b,
                            const float* __restrict__ fc2_w, const float* __restrict__ fc2_b,
                            float* __restrict__ attn) {
    int b = threadIdx.x;
    if (b >= BB) return;
    float h[KK];
    #pragma unroll
    for (int k = 0; k < KK; ++k) {
        float s = fc1_b[k];
        for (int c = 0; c < CC; ++c) s += pooled[b*CC + c] * fc1_w[k*CC + c];
        h[k] = fmaxf(s, 0.f);
    }
    float z[KK]; float m = -1e30f;
    #pragma unroll
    for (int k = 0; k < KK; ++k) {
        float s = fc2_b[k];
        #pragma unroll
        for (int j = 0; j < KK; ++j) s += h[j] * fc2_w[k*KK + j];
        z[k] = s; m = fmaxf(m, s);
    }
    float den = 0.f;
    #pragma unroll
    for (int k = 0; k < KK; ++k) { z[k] = expf(z[k] - m); den += z[k]; }
    #pragma unroll
    for (int k = 0; k < KK; ++k) attn[b*KK + k] = z[k] / den;
}

// ---------------- agg_b[b,o] = sum_k attn[b,k] * bias[k,o] ----------------
__global__ void aggb_kernel(const float* __restrict__ attn, const float* __restrict__ bias,
                            float* __restrict__ agg_b) {
    int idx = blockIdx.x * blockDim.x + threadIdx.x;   // 4096 = BB*OO
    if (idx >= BB * OO) return;
    int b = idx >> 7, o = idx & 127;
    float s = 0.f;
    #pragma unroll
    for (int k = 0; k < KK; ++k) s += attn[b*KK + k] * bias[k*OO + o];
    agg_b[idx] = s;
}

// ---------------- per-sample conv 3x3, pad 1 ----------------
// block: (h-tile 0..6, o-tile 0..7, b 0..31); 256 threads.
// Each block: 16 output channels x 8 rows x 56 cols for one sample.
// Thread (tid<224): px = tid%56, owns rows r0=2*(tid/56) and r0+1.
// Per 8-channel chunk: stage x tile [8][10][58] (zero-padded) and
// aggregated weights built on the fly from global weight (L2-resident).
__launch_bounds__(256)
__global__ void conv_kernel(const float* __restrict__ x, const float* __restrict__ weight,
                            const float* __restrict__ attn, const float* __restrict__ agg_b,
                            float* __restrict__ out) {
    const int h0 = blockIdx.x * 8;
    const int o0 = blockIdx.y * 16;
    const int b  = blockIdx.z;
    __shared__ float xs[8 * 10 * 58];      // 4640 floats
    __shared__ float wsm[16 * 8 * 12];     // padded [o][c][12], 9 used
    const int tid = threadIdx.x;
    const int px = tid % 56;
    const int r0 = (tid / 56) * 2;
    const bool act = tid < 224;

    const float a0 = attn[b*KK + 0], a1 = attn[b*KK + 1],
                a2 = attn[b*KK + 2], a3 = attn[b*KK + 3];

    float acc0[16], acc1[16];
    #pragma unroll
    for (int o = 0; o < 16; ++o) { acc0[o] = 0.f; acc1[o] = 0.f; }

    for (int c0 = 0; c0 < CC; c0 += 8) {
        __syncthreads();
        // stage x tile: rows h0-1 .. h0+8, cols -1 .. 56 (zero-padded)
        for (int e = tid; e < 4640; e += 256) {
            int c = e / 580, rem = e - c * 580;
            int r = rem / 58, col = rem - r * 58;
            int gh = h0 - 1 + r, gx = col - 1;
            float v = 0.f;
            if (gh >= 0 && gh < HH && gx >= 0 && gx < WW)
                v = x[((size_t)(b*CC + c0 + c)) * HW + gh*WW + gx];
            xs[e] = v;
        }
        // stage aggregated weights for this chunk (built on the fly)
        for (int e = tid; e < 1152; e += 256) {
            int o = e / 72, rem = e - o * 72;
            int c = rem / 9, j = rem - c * 9;
            size_t wi = ((size_t)((o0 + o)*CC + c0 + c)) * 9 + j;
            wsm[o*96 + c*12 + j] = a0 * weight[wi]
                                 + a1 * weight[wi + (size_t)WPLANE]
                                 + a2 * weight[wi + (size_t)2*WPLANE]
                                 + a3 * weight[wi + (size_t)3*WPLANE];
        }
        __syncthreads();
        if (act) {
            #pragma unroll
            for (int c = 0; c < 8; ++c) {
                float xt[4][3];
                #pragma unroll
                for (int jr = 0; jr < 4; ++jr)
                    #pragma unroll
                    for (int jx = 0; jx < 3; ++jx)
                        xt[jr][jx] = xs[c*580 + (r0 + jr)*58 + px + jx];
                #pragma unroll
                for (int o = 0; o < 16; ++o) {
                    const float* wp = &wsm[o*96 + c*12];
                    float w0=wp[0],w1=wp[1],w2=wp[2],w3=wp[3],w4=wp[4],
                          w5=wp[5],w6=wp[6],w7=wp[7],w8=wp[8];
                    acc0[o] += w0*xt[0][0] + w1*xt[0][1] + w2*xt[0][2]
                             + w3*xt[1][0] + w4*xt[1][1] + w5*xt[1][2]
                             + w6*xt[2][0] + w7*xt[2][1] + w8*xt[2][2];
                    acc1[o] += w0*xt[1][0] + w1*xt[1][1] + w2*xt[1][2]
                             + w3*xt[2][0] + w4*xt[2][1] + w5*xt[2][2]
                             + w6*xt[3][0] + w7*xt[3][1] + w8*xt[3][2];
                }
            }
        }
    }
    if (act) {
        #pragma unroll
        for (int o = 0; o < 16; ++o) {
            float bb_ = agg_b[b*OO + o0 + o];
            size_t base = ((size_t)(b*OO + o0 + o)) * HW + (h0 + r0)*WW + px;
            out[base]      = acc0[o] + bb_;
            out[base + WW] = acc1[o] + bb_;
        }
    }
}

// ---------------- per-(b,o) partial sums (deterministic) ----------------
__global__ void stats_kernel(const float* __restrict__ out,
                             float* __restrict__ psum, float* __restrict__ psumsq) {
    int bo = blockIdx.x;
    const float* p = out + (size_t)bo * HW;
    float s = 0.f, s2 = 0.f;
    for (int e = threadIdx.x; e < HW; e += 256) { float v = p[e]; s += v; s2 += v*v; }
    for (int off = 32; off > 0; off >>= 1) {
        s  += __shfl_down(s, off, 64);
        s2 += __shfl_down(s2, off, 64);
    }
    __shared__ float r1[4], r2[4];
    int wid = threadIdx.x >> 6, lane = threadIdx.x & 63;
    if (lane == 0) { r1[wid] = s; r2[wid] = s2; }
    __syncthreads();
    if (threadIdx.x == 0) {
        psum[bo]   = r1[0] + r1[1] + r1[2] + r1[3];
        psumsq[bo] = r2[0] + r2[1] + r2[2] + r2[3];
    }
}

__global__ void finstats_kernel(const float* __restrict__ psum, const float* __restrict__ psumsq,
                                float* __restrict__ sums, float* __restrict__ sumsq) {
    int o = threadIdx.x;   // 128
    float s = 0.f, s2 = 0.f;
    for (int b = 0; b < BB; ++b) { s += psum[b*OO + o]; s2 += psumsq[b*OO + o]; }
    sums[o] = s; sumsq[o] = s2;
}

// ---------------- BN (training stats) + ReLU, in place ----------------
__global__ void bn_kernel(float* __restrict__ out,
                          const float* __restrict__ sums, const float* __restrict__ sumsq,
                          const float* __restrict__ gamma, const float* __restrict__ beta) {
    const float invN = 1.0f / (float)(BB * HW);
    const int total4 = BB * OO * HW / 4;
    for (int i = blockIdx.x * blockDim.x + threadIdx.x; i < total4; i += gridDim.x * blockDim.x) {
        int o = (i / (HW/4)) % OO;
        float mean = sums[o] * invN;
        float var  = sumsq[o] * invN - mean*mean;
        float inv  = rsqrtf(var + EPSV);
        float g  = gamma[o] * inv;
        float bt = beta[o] - mean * g;
        float4 v = ((float4*)out)[i];
        v.x = fmaxf(v.x*g + bt, 0.f);
        v.y = fmaxf(v.y*g + bt, 0.f);
        v.z = fmaxf(v.z*g + bt, 0.f);
        v.w = fmaxf(v.w*g + bt, 0.f);
        ((float4*)out)[i] = v;
    }
}

extern "C" void kernel_launch(void* const* d_in, const int* in_sizes, int n_in,
                              void* d_out, int out_size, void* d_ws, size_t ws_size,
                              hipStream_t stream) {
    const float* x      = (const float*)d_in[0];
    const float* fc1_w  = (const float*)d_in[1];
    const float* fc1_b  = (const float*)d_in[2];
    const float* fc2_w  = (const float*)d_in[3];
    const float* fc2_b  = (const float*)d_in[4];
    const float* weight = (const float*)d_in[5];
    const float* bias   = (const float*)d_in[6];
    const float* gamma  = (const float*)d_in[7];
    const float* beta   = (const float*)d_in[8];
    float* out = (float*)d_out;

    float* wsf    = (float*)d_ws;
    float* pooled = wsf;            // 4096
    float* attn   = wsf + 4096;     // 128
    float* agg_b  = wsf + 4224;     // 4096
    float* psum   = wsf + 8320;     // 4096
    float* psumsq = wsf + 12416;    // 4096
    float* sums   = wsf + 16512;    // 128
    float* sumsq  = wsf + 16640;    // 128  -> total 16768 floats (~67 KB)

    pool_kernel<<<BB*CC, 256, 0, stream>>>(x, pooled);
    attn_kernel<<<1, 64, 0, stream>>>(pooled, fc1_w, fc1_b, fc2_w, fc2_b, attn);
    aggb_kernel<<<(BB*OO + 255)/256, 256, 0, stream>>>(attn, bias, agg_b);
    conv_kernel<<<dim3(7, 8, BB), 256, 0, stream>>>(x, weight, attn, agg_b, out);
    stats_kernel<<<BB*OO, 256, 0, stream>>>(out, psum, psumsq);
    finstats_kernel<<<1, 128, 0, stream>>>(psum, psumsq, sums, sumsq);
    bn_kernel<<<2048, 256, 0, stream>>>(out, sums, sumsq, gamma, beta);
}

// Round 2
// 178.300 us; speedup vs baseline: 14.0278x; 14.0278x over previous
//
#include <hip/hip_runtime.h>
#include <hip/hip_bf16.h>

// Problem constants
#define BB 32
#define CC 128
#define OO 128
#define HH 56
#define WW 56
#define KK 4
#define HW 3136           // 56*56
#define WPLANE 147456     // OO*CC*9, per-k weight plane stride
#define EPSV 1e-5f

typedef __attribute__((ext_vector_type(8))) short short8v;   // bf16x8 fragment
typedef __attribute__((ext_vector_type(4))) float f32x4;     // mfma C/D

// ---------------- pooled = mean over H,W per (b,c) ----------------
__global__ void pool_kernel(const float* __restrict__ x, float* __restrict__ pooled) {
    int bc = blockIdx.x;
    const float* p = x + (size_t)bc * HW;
    float s = 0.f;
    for (int e = threadIdx.x; e < HW; e += 256) s += p[e];
    for (int off = 32; off > 0; off >>= 1) s += __shfl_down(s, off, 64);
    __shared__ float red[4];
    int wid = threadIdx.x >> 6, lane = threadIdx.x & 63;
    if (lane == 0) red[wid] = s;
    __syncthreads();
    if (threadIdx.x == 0)
        pooled[bc] = (red[0] + red[1] + red[2] + red[3]) * (1.0f / HW);
}

// ---------------- attention MLP + softmax ----------------
__global__ void attn_kernel(const float* __restrict__ pooled,
                            const float* __restrict__ fc1_w, const float* __restrict__ fc1_b,
                            const float* __restrict__ fc2_w, const float* __restrict__ fc2_b,
                            float* __restrict__ attn) {
    int b = threadIdx.x;
    if (b >= BB) return;
    float h[KK];
    #pragma unroll
    for (int k = 0; k < KK; ++k) {
        float s = fc1_b[k];
        for (int c = 0; c < CC; ++c) s += pooled[b*CC + c] * fc1_w[k*CC + c];
        h[k] = fmaxf(s, 0.f);
    }
    float z[KK]; float m = -1e30f;
    #pragma unroll
    for (int k = 0; k < KK; ++k) {
        float s = fc2_b[k];
        #pragma unroll
        for (int j = 0; j < KK; ++j) s += h[j] * fc2_w[k*KK + j];
        z[k] = s; m = fmaxf(m, s);
    }
    float den = 0.f;
    #pragma unroll
    for (int k = 0; k < KK; ++k) { z[k] = expf(z[k] - m); den += z[k]; }
    #pragma unroll
    for (int k = 0; k < KK; ++k) attn[b*KK + k] = z[k] / den;
}

// ---------------- agg_w[b][j][o][c] (bf16) = sum_k attn[b,k] * weight[k][o][c][j] ----------------
__global__ void aggw_kernel(const float* __restrict__ attn, const float* __restrict__ weight,
                            ushort* __restrict__ aggw) {
    int idx = blockIdx.x * 256 + threadIdx.x;       // 32*9*128*128 = 4,718,592
    if (idx >= BB * 9 * OO * CC) return;
    int c = idx & 127;
    int t = idx >> 7;
    int o = t & 127;
    t >>= 7;
    int j = t % 9;
    int b = t / 9;
    size_t wi = ((size_t)(o * CC + c)) * 9 + j;
    float s = attn[b*KK + 0] * weight[wi]
            + attn[b*KK + 1] * weight[wi + (size_t)WPLANE]
            + attn[b*KK + 2] * weight[wi + (size_t)2*WPLANE]
            + attn[b*KK + 3] * weight[wi + (size_t)3*WPLANE];
    __hip_bfloat16 hb = __float2bfloat16(s);
    aggw[idx] = *(ushort*)&hb;
}

// ---------------- agg_b[b,o] ----------------
__global__ void aggb_kernel(const float* __restrict__ attn, const float* __restrict__ bias,
                            float* __restrict__ agg_b) {
    int idx = blockIdx.x * blockDim.x + threadIdx.x;
    if (idx >= BB * OO) return;
    int b = idx >> 7, o = idx & 127;
    float s = 0.f;
    #pragma unroll
    for (int k = 0; k < KK; ++k) s += attn[b*KK + k] * bias[k*OO + o];
    agg_b[idx] = s;
}

// ---------------- implicit-GEMM conv via MFMA ----------------
// Block: (h-tile 0..13, b). Output: all 128 o x (4 rows x 56 cols = 224 = 14x16 frags).
// 4 waves: wave(wx,wy) owns o in [wx*64, wx*64+64) x p in [wy*112, wy*112+112):
// Mf=4, Nf=7 fragments of 16x16, K = 9 taps x 128 channels, c-chunked by 32.
// LDS x tile: [6 rows][58 cols][40 c-pad] bf16 (32 channels used), 16B-aligned b128 reads.
__launch_bounds__(256)
__global__ void conv_kernel(const float* __restrict__ x, const ushort* __restrict__ aggw,
                            const float* __restrict__ agg_b, float* __restrict__ out) {
    const int h0 = blockIdx.x * 4;
    const int b  = blockIdx.y;
    __shared__ ushort xs[6 * 58 * 40];          // 27840 B

    const int tid  = threadIdx.x;
    const int lane = tid & 63;
    const int wid  = tid >> 6;
    const int wx = wid >> 1;                    // o half
    const int wy = wid & 1;                     // p half
    const int cf = lane & 15;                   // frag col / A row
    const int kg = lane >> 4;                   // k-group

    int bofs[7];                                // LDS byte offsets per N-frag
    int oofs[7];                                // global spatial offsets per N-frag
    #pragma unroll
    for (int nf = 0; nf < 7; ++nf) {
        int p = wy*112 + nf*16 + cf;
        int r = p / 56, w = p - r*56;
        bofs[nf] = (((r + 1)*58 + (w + 1))*40 + kg*8) * 2;
        oofs[nf] = (h0 + r)*WW + w;
    }

    f32x4 acc[4][7];
    #pragma unroll
    for (int mf = 0; mf < 4; ++mf)
        #pragma unroll
        for (int nf = 0; nf < 7; ++nf) acc[mf][nf] = (f32x4){0.f,0.f,0.f,0.f};

    const ushort* Aw = aggw + (size_t)b*9*16384 + (size_t)(wx*64 + cf)*128;

    for (int c0 = 0; c0 < CC; c0 += 32) {
        __syncthreads();
        // stage x[b][c0..c0+31] rows h0-1..h0+4, cols -1..56 -> LDS bf16 [row][col][c]
        for (int e = tid; e < 2784; e += 256) {          // 2784 = 8 cgroups * 6 * 58
            int cg  = e / 348;
            int rem = e - cg*348;
            int row = rem / 58, col = rem - row*58;
            int gh = h0 - 1 + row, gw = col - 1;
            int c  = c0 + cg*4;
            ushort4 v = {0, 0, 0, 0};
            if (gh >= 0 && gh < HH && gw >= 0 && gw < WW) {
                const float* xp = x + ((size_t)(b*CC + c))*HW + gh*WW + gw;
                __hip_bfloat16 b0 = __float2bfloat16(xp[0]);
                __hip_bfloat16 b1 = __float2bfloat16(xp[HW]);
                __hip_bfloat16 b2 = __float2bfloat16(xp[2*HW]);
                __hip_bfloat16 b3 = __float2bfloat16(xp[3*HW]);
                v.x = *(ushort*)&b0; v.y = *(ushort*)&b1;
                v.z = *(ushort*)&b2; v.w = *(ushort*)&b3;
            }
            *(ushort4*)(&xs[(row*58 + col)*40 + cg*4]) = v;
        }
        __syncthreads();

        #pragma unroll
        for (int j = 0; j < 9; ++j) {
            const int dh = j/3 - 1, dw = j%3 - 1;
            const int toff = (dh*58 + dw) * 80;          // bytes
            short8v afr[4];
            #pragma unroll
            for (int mf = 0; mf < 4; ++mf)
                afr[mf] = *(const short8v*)(Aw + (size_t)j*16384 + mf*2048 + c0 + kg*8);
            #pragma unroll
            for (int nf = 0; nf < 7; ++nf) {
                short8v bfr = *(const short8v*)((const char*)xs + bofs[nf] + toff);
                #pragma unroll
                for (int mf = 0; mf < 4; ++mf)
                    acc[mf][nf] = __builtin_amdgcn_mfma_f32_16x16x32_bf16(
                        afr[mf], bfr, acc[mf][nf], 0, 0, 0);
            }
        }
    }

    // epilogue: D row = mf*16 + kg*4 + i (o), col = cf (position)
    #pragma unroll
    for (int mf = 0; mf < 4; ++mf) {
        #pragma unroll
        for (int i = 0; i < 4; ++i) {
            int o = wx*64 + mf*16 + kg*4 + i;
            float bb_ = agg_b[b*OO + o];
            float* op = out + ((size_t)(b*OO + o))*HW;
            #pragma unroll
            for (int nf = 0; nf < 7; ++nf)
                op[oofs[nf]] = acc[mf][nf][i] + bb_;
        }
    }
}

// ---------------- per-(b,o) partial sums ----------------
__global__ void stats_kernel(const float* __restrict__ out,
                             float* __restrict__ psum, float* __restrict__ psumsq) {
    int bo = blockIdx.x;
    const float* p = out + (size_t)bo * HW;
    float s = 0.f, s2 = 0.f;
    for (int e = threadIdx.x; e < HW; e += 256) { float v = p[e]; s += v; s2 += v*v; }
    for (int off = 32; off > 0; off >>= 1) {
        s  += __shfl_down(s, off, 64);
        s2 += __shfl_down(s2, off, 64);
    }
    __shared__ float r1[4], r2[4];
    int wid = threadIdx.x >> 6, lane = threadIdx.x & 63;
    if (lane == 0) { r1[wid] = s; r2[wid] = s2; }
    __syncthreads();
    if (threadIdx.x == 0) {
        psum[bo]   = r1[0] + r1[1] + r1[2] + r1[3];
        psumsq[bo] = r2[0] + r2[1] + r2[2] + r2[3];
    }
}

__global__ void finstats_kernel(const float* __restrict__ psum, const float* __restrict__ psumsq,
                                float* __restrict__ sums, float* __restrict__ sumsq) {
    int o = threadIdx.x;
    float s = 0.f, s2 = 0.f;
    for (int b = 0; b < BB; ++b) { s += psum[b*OO + o]; s2 += psumsq[b*OO + o]; }
    sums[o] = s; sumsq[o] = s2;
}

// ---------------- BN (training stats) + ReLU, in place ----------------
__global__ void bn_kernel(float* __restrict__ out,
                          const float* __restrict__ sums, const float* __restrict__ sumsq,
                          const float* __restrict__ gamma, const float* __restrict__ beta) {
    const float invN = 1.0f / (float)(BB * HW);
    const int total4 = BB * OO * HW / 4;
    for (int i = blockIdx.x * blockDim.x + threadIdx.x; i < total4; i += gridDim.x * blockDim.x) {
        int o = (i / (HW/4)) % OO;
        float mean = sums[o] * invN;
        float var  = sumsq[o] * invN - mean*mean;
        float inv  = rsqrtf(var + EPSV);
        float g  = gamma[o] * inv;
        float bt = beta[o] - mean * g;
        float4 v = ((float4*)out)[i];
        v.x = fmaxf(v.x*g + bt, 0.f);
        v.y = fmaxf(v.y*g + bt, 0.f);
        v.z = fmaxf(v.z*g + bt, 0.f);
        v.w = fmaxf(v.w*g + bt, 0.f);
        ((float4*)out)[i] = v;
    }
}

extern "C" void kernel_launch(void* const* d_in, const int* in_sizes, int n_in,
                              void* d_out, int out_size, void* d_ws, size_t ws_size,
                              hipStream_t stream) {
    const float* x      = (const float*)d_in[0];
    const float* fc1_w  = (const float*)d_in[1];
    const float* fc1_b  = (const float*)d_in[2];
    const float* fc2_w  = (const float*)d_in[3];
    const float* fc2_b  = (const float*)d_in[4];
    const float* weight = (const float*)d_in[5];
    const float* bias   = (const float*)d_in[6];
    const float* gamma  = (const float*)d_in[7];
    const float* beta   = (const float*)d_in[8];
    float* out = (float*)d_out;

    // workspace layout: agg_w (bf16) first, then small float buffers
    const size_t AGGW_ELEMS = (size_t)BB * 9 * OO * CC;      // 4,718,592
    ushort* aggw = (ushort*)d_ws;
    float*  wsf  = (float*)((char*)d_ws + AGGW_ELEMS * sizeof(ushort));  // 9.44 MB offset
    float* pooled = wsf;            // 4096
    float* attn   = wsf + 4096;     // 128
    float* agg_b  = wsf + 4224;     // 4096
    float* psum   = wsf + 8320;     // 4096
    float* psumsq = wsf + 12416;    // 4096
    float* sums   = wsf + 16512;    // 128
    float* sumsq  = wsf + 16640;    // 128

    pool_kernel<<<BB*CC, 256, 0, stream>>>(x, pooled);
    attn_kernel<<<1, 64, 0, stream>>>(pooled, fc1_w, fc1_b, fc2_w, fc2_b, attn);
    aggw_kernel<<<(int)((AGGW_ELEMS + 255)/256), 256, 0, stream>>>(attn, weight, aggw);
    aggb_kernel<<<(BB*OO + 255)/256, 256, 0, stream>>>(attn, bias, agg_b);
    conv_kernel<<<dim3(14, BB), 256, 0, stream>>>(x, aggw, agg_b, out);
    stats_kernel<<<BB*OO, 256, 0, stream>>>(out, psum, psumsq);
    finstats_kernel<<<1, 128, 0, stream>>>(psum, psumsq, sums, sumsq);
    bn_kernel<<<2048, 256, 0, stream>>>(out, sums, sumsq, gamma, beta);
}

// Round 3
// 135.462 us; speedup vs baseline: 18.4639x; 1.3162x over previous
//
#include <hip/hip_runtime.h>
#include <hip/hip_bf16.h>

#define BB 32
#define CC 128
#define OO 128
#define HH 56
#define WW 56
#define KK 4
#define HW 3136
#define WPLANE 147456
#define EPSV 1e-5f

#define NPOS 348          // 6*58 staged positions
#define PSTR 40           // shorts per position (80 B; 64 B data + 16 B pad)
#define CHUNK_SH (NPOS*PSTR)

typedef __attribute__((ext_vector_type(8))) short short8v;
typedef __attribute__((ext_vector_type(4))) float f32x4;

// ---- convert x -> bf16 channel-last [b][h][w][c], + per-(b,h,c) row sums ----
__global__ void convert_pool_kernel(const float* __restrict__ x,
                                    ushort* __restrict__ xbf,
                                    float* __restrict__ pooledp) {
    const int h = blockIdx.x, b = blockIdx.y;
    __shared__ float xl[128 * 57];
    const float* xp = x + (size_t)(b * CC) * HW + h * WW;
    #pragma unroll
    for (int k = 0; k < 28; ++k) {
        int e = threadIdx.x + k * 256;          // 7168 elems
        int c = e / 56, w = e - c * 56;
        xl[c * 57 + w] = xp[(size_t)c * HW + w];
    }
    __syncthreads();
    // write transposed bf16
    ushort* op = xbf + ((size_t)(b * HH + h)) * WW * CC;
    #pragma unroll
    for (int k = 0; k < 7; ++k) {
        int f = threadIdx.x + k * 256;          // 1792 ushort4 units
        int w = f >> 5, c4 = (f & 31) * 4;
        ushort4 v;
        __hip_bfloat16 b0 = __float2bfloat16(xl[(c4 + 0) * 57 + w]);
        __hip_bfloat16 b1 = __float2bfloat16(xl[(c4 + 1) * 57 + w]);
        __hip_bfloat16 b2 = __float2bfloat16(xl[(c4 + 2) * 57 + w]);
        __hip_bfloat16 b3 = __float2bfloat16(xl[(c4 + 3) * 57 + w]);
        v.x = *(ushort*)&b0; v.y = *(ushort*)&b1;
        v.z = *(ushort*)&b2; v.w = *(ushort*)&b3;
        *(ushort4*)(op + (size_t)w * CC + c4) = v;
    }
    if (threadIdx.x < 128) {
        int c = threadIdx.x;
        float s = 0.f;
        #pragma unroll
        for (int w = 0; w < 56; ++w) s += xl[c * 57 + w];
        pooledp[((size_t)(b * HH + h)) * CC + c] = s;
    }
}

// ---- attention: reduce pooled partials + tiny MLP + softmax. block per b ----
__global__ void attn_kernel(const float* __restrict__ pooledp,
                            const float* __restrict__ fc1_w, const float* __restrict__ fc1_b,
                            const float* __restrict__ fc2_w, const float* __restrict__ fc2_b,
                            float* __restrict__ attn) {
    const int b = blockIdx.x, c = threadIdx.x;      // 128 threads
    float s = 0.f;
    for (int h = 0; h < HH; ++h) s += pooledp[((size_t)(b * HH + h)) * CC + c];
    const float pc = s * (1.0f / HW);
    __shared__ float red[8];
    const int lane = c & 63, wid = c >> 6;
    #pragma unroll
    for (int k = 0; k < KK; ++k) {
        float v = pc * fc1_w[k * CC + c];
        for (int off = 32; off > 0; off >>= 1) v += __shfl_down(v, off, 64);
        if (lane == 0) red[k * 2 + wid] = v;
    }
    __syncthreads();
    if (c == 0) {
        float hk[KK], z[KK], m = -1e30f, den = 0.f;
        #pragma unroll
        for (int k = 0; k < KK; ++k)
            hk[k] = fmaxf(red[k * 2] + red[k * 2 + 1] + fc1_b[k], 0.f);
        #pragma unroll
        for (int k = 0; k < KK; ++k) {
            float t = fc2_b[k];
            #pragma unroll
            for (int j = 0; j < KK; ++j) t += hk[j] * fc2_w[k * KK + j];
            z[k] = t; m = fmaxf(m, t);
        }
        #pragma unroll
        for (int k = 0; k < KK; ++k) { z[k] = expf(z[k] - m); den += z[k]; }
        #pragma unroll
        for (int k = 0; k < KK; ++k) attn[b * KK + k] = z[k] / den;
    }
}

// ---- agg_w[b][j][o][c] (bf16) ----
__global__ void aggw_kernel(const float* __restrict__ attn, const float* __restrict__ weight,
                            ushort* __restrict__ aggw) {
    int idx = blockIdx.x * 256 + threadIdx.x;
    if (idx >= BB * 9 * OO * CC) return;
    int c = idx & 127;
    int t = idx >> 7;
    int o = t & 127;
    t >>= 7;
    int j = t % 9;
    int b = t / 9;
    size_t wi = ((size_t)(o * CC + c)) * 9 + j;
    float s = attn[b*KK + 0] * weight[wi]
            + attn[b*KK + 1] * weight[wi + (size_t)WPLANE]
            + attn[b*KK + 2] * weight[wi + (size_t)2*WPLANE]
            + attn[b*KK + 3] * weight[wi + (size_t)3*WPLANE];
    __hip_bfloat16 hb = __float2bfloat16(s);
    aggw[idx] = *(ushort*)&hb;
}

__global__ void aggb_kernel(const float* __restrict__ attn, const float* __restrict__ bias,
                            float* __restrict__ agg_b) {
    int idx = blockIdx.x * blockDim.x + threadIdx.x;
    if (idx >= BB * OO) return;
    int b = idx >> 7, o = idx & 127;
    float s = 0.f;
    #pragma unroll
    for (int k = 0; k < KK; ++k) s += attn[b*KK + k] * bias[k*OO + o];
    agg_b[idx] = s;
}

// ---- implicit-GEMM conv, 8 waves, double-buffered LDS, fused stats partials ----
__launch_bounds__(512, 4)
__global__ void conv_kernel(const ushort* __restrict__ xbf, const ushort* __restrict__ aggw,
                            const float* __restrict__ agg_b, float* __restrict__ out,
                            float* __restrict__ psum, float* __restrict__ psumsq) {
    const int t  = blockIdx.x;           // h-tile 0..13
    const int h0 = t * 4;
    const int b  = blockIdx.y;
    __shared__ ushort xs[2 * CHUNK_SH];  // 55680 B

    const int tid  = threadIdx.x;
    const int lane = tid & 63;
    const int wid  = tid >> 6;
    const int wg = wid & 3;              // o-group: o base = wg*32
    const int wy = wid >> 2;             // p base = wy*112
    const int cf = lane & 15;
    const int kg = lane >> 4;

    // ---- staging assignments: units 0..1391 (pos*4 + quad) ----
    int spos[3]; const ushort* sga[3]; bool lv[3]; bool wv[3];
    #pragma unroll
    for (int u = 0; u < 3; ++u) {
        int un = tid + u * 512;
        wv[u] = un < 1392;
        int pos = un >> 2, quad = un & 3;
        int row = pos / 58, col = pos - row * 58;
        int gh = h0 - 1 + row, gw = col - 1;
        lv[u] = wv[u] && gh >= 0 && gh < HH && gw >= 0 && gw < WW;
        spos[u] = pos * PSTR + quad * 8;
        sga[u] = xbf + ((size_t)((b * HH + gh) * WW + gw)) * CC + quad * 8;
    }

    // B-frag LDS byte offsets + output offsets
    int bofs[7], oofs[7];
    #pragma unroll
    for (int nf = 0; nf < 7; ++nf) {
        int p = wy * 112 + nf * 16 + cf;
        int r = p / 56, w = p - r * 56;
        bofs[nf] = (((r + 1) * 58 + (w + 1)) * PSTR + kg * 8) * 2;
        oofs[nf] = (h0 + r) * WW + w;
    }

    f32x4 acc[2][7];
    #pragma unroll
    for (int mf = 0; mf < 2; ++mf)
        #pragma unroll
        for (int nf = 0; nf < 7; ++nf) acc[mf][nf] = (f32x4){0.f, 0.f, 0.f, 0.f};

    const ushort* Abase = aggw + (size_t)b * 9 * 16384 + (size_t)(wg * 32 + cf) * 128;

    const short8v zero8 = (short8v){0,0,0,0,0,0,0,0};
    short8v sreg[3];

    // prologue: chunk 0
    #pragma unroll
    for (int u = 0; u < 3; ++u) {
        sreg[u] = zero8;
        if (lv[u]) sreg[u] = *(const short8v*)(sga[u]);
    }
    #pragma unroll
    for (int u = 0; u < 3; ++u)
        if (wv[u]) *(short8v*)(xs + spos[u]) = sreg[u];

    int cur = 0;
    for (int ci = 0; ci < 4; ++ci) {
        const int c0 = ci * 32;
        if (ci < 3) {
            #pragma unroll
            for (int u = 0; u < 3; ++u) {
                sreg[u] = zero8;
                if (lv[u]) sreg[u] = *(const short8v*)(sga[u] + c0 + 32);
            }
        }
        __syncthreads();
        const ushort* xb = xs + cur * CHUNK_SH;
        #pragma unroll
        for (int j = 0; j < 9; ++j) {
            const int toff = ((j/3 - 1) * 58 + (j%3 - 1)) * (PSTR * 2);
            short8v a0 = *(const short8v*)(Abase + (size_t)j * 16384 + c0 + kg * 8);
            short8v a1 = *(const short8v*)(Abase + (size_t)j * 16384 + 2048 + c0 + kg * 8);
            #pragma unroll
            for (int nf = 0; nf < 7; ++nf) {
                short8v bf = *(const short8v*)((const char*)xb + bofs[nf] + toff);
                acc[0][nf] = __builtin_amdgcn_mfma_f32_16x16x32_bf16(a0, bf, acc[0][nf], 0, 0, 0);
                acc[1][nf] = __builtin_amdgcn_mfma_f32_16x16x32_bf16(a1, bf, acc[1][nf], 0, 0, 0);
            }
        }
        if (ci < 3) {
            ushort* xw = xs + (cur ^ 1) * CHUNK_SH;
            #pragma unroll
            for (int u = 0; u < 3; ++u)
                if (wv[u]) *(short8v*)(xw + spos[u]) = sreg[u];
            cur ^= 1;
        }
    }

    // ---- epilogue: bias add, store, fused stats partials ----
    #pragma unroll
    for (int mf = 0; mf < 2; ++mf) {
        #pragma unroll
        for (int i = 0; i < 4; ++i) {
            const int o = wg * 32 + mf * 16 + kg * 4 + i;
            const float ab = agg_b[b * OO + o];
            float* op = out + ((size_t)(b * OO + o)) * HW;
            float s = 0.f, s2 = 0.f;
            #pragma unroll
            for (int nf = 0; nf < 7; ++nf) {
                float v = acc[mf][nf][i] + ab;
                op[oofs[nf]] = v;
                s += v; s2 += v * v;
            }
            s  += __shfl_xor(s, 1, 64);  s  += __shfl_xor(s, 2, 64);
            s  += __shfl_xor(s, 4, 64);  s  += __shfl_xor(s, 8, 64);
            s2 += __shfl_xor(s2, 1, 64); s2 += __shfl_xor(s2, 2, 64);
            s2 += __shfl_xor(s2, 4, 64); s2 += __shfl_xor(s2, 8, 64);
            if (cf == 0) {
                int row = (b * 14 + t) * 2 + wy;
                psum[row * OO + o]   = s;
                psumsq[row * OO + o] = s2;
            }
        }
    }
}

// ---- final stats: one block per channel ----
__global__ void finstats_kernel(const float* __restrict__ psum, const float* __restrict__ psumsq,
                                float* __restrict__ sums, float* __restrict__ sumsq) {
    const int o = blockIdx.x, l = threadIdx.x;   // 64 threads
    float s = 0.f, s2 = 0.f;
    for (int r = l; r < 896; r += 64) { s += psum[r * OO + o]; s2 += psumsq[r * OO + o]; }
    for (int off = 32; off > 0; off >>= 1) {
        s  += __shfl_down(s, off, 64);
        s2 += __shfl_down(s2, off, 64);
    }
    if (l == 0) { sums[o] = s; sumsq[o] = s2; }
}

// ---- BN + ReLU in place ----
__global__ void bn_kernel(float* __restrict__ out,
                          const float* __restrict__ sums, const float* __restrict__ sumsq,
                          const float* __restrict__ gamma, const float* __restrict__ beta) {
    const float invN = 1.0f / (float)(BB * HW);
    const int total4 = BB * OO * HW / 4;
    for (int i = blockIdx.x * blockDim.x + threadIdx.x; i < total4; i += gridDim.x * blockDim.x) {
        int o = (i / (HW/4)) % OO;
        float mean = sums[o] * invN;
        float var  = sumsq[o] * invN - mean*mean;
        float inv  = rsqrtf(var + EPSV);
        float g  = gamma[o] * inv;
        float bt = beta[o] - mean * g;
        float4 v = ((float4*)out)[i];
        v.x = fmaxf(v.x*g + bt, 0.f);
        v.y = fmaxf(v.y*g + bt, 0.f);
        v.z = fmaxf(v.z*g + bt, 0.f);
        v.w = fmaxf(v.w*g + bt, 0.f);
        ((float4*)out)[i] = v;
    }
}

extern "C" void kernel_launch(void* const* d_in, const int* in_sizes, int n_in,
                              void* d_out, int out_size, void* d_ws, size_t ws_size,
                              hipStream_t stream) {
    const float* x      = (const float*)d_in[0];
    const float* fc1_w  = (const float*)d_in[1];
    const float* fc1_b  = (const float*)d_in[2];
    const float* fc2_w  = (const float*)d_in[3];
    const float* fc2_b  = (const float*)d_in[4];
    const float* weight = (const float*)d_in[5];
    const float* bias   = (const float*)d_in[6];
    const float* gamma  = (const float*)d_in[7];
    const float* beta   = (const float*)d_in[8];
    float* out = (float*)d_out;

    const size_t XBF_ELEMS  = (size_t)BB * HW * CC;        // 12,845,056
    const size_t AGGW_ELEMS = (size_t)BB * 9 * OO * CC;    //  4,718,592
    ushort* xbf  = (ushort*)d_ws;
    ushort* aggw = xbf + XBF_ELEMS;
    float*  wsf  = (float*)(aggw + AGGW_ELEMS);
    float* pooledp = wsf;                    // 229376
    float* attn    = pooledp + 229376;       // 128
    float* agg_b   = attn + 128;             // 4096
    float* psum    = agg_b + 4096;           // 114688
    float* psumsq  = psum + 114688;          // 114688
    float* sums    = psumsq + 114688;        // 128
    float* sumsq   = sums + 128;             // 128

    convert_pool_kernel<<<dim3(HH, BB), 256, 0, stream>>>(x, xbf, pooledp);
    attn_kernel<<<BB, 128, 0, stream>>>(pooledp, fc1_w, fc1_b, fc2_w, fc2_b, attn);
    aggw_kernel<<<(int)((AGGW_ELEMS + 255)/256), 256, 0, stream>>>(attn, weight, aggw);
    aggb_kernel<<<(BB*OO + 255)/256, 256, 0, stream>>>(attn, bias, agg_b);
    conv_kernel<<<dim3(14, BB), 512, 0, stream>>>(xbf, aggw, agg_b, out, psum, psumsq);
    finstats_kernel<<<OO, 64, 0, stream>>>(psum, psumsq, sums, sumsq);
    bn_kernel<<<2048, 256, 0, stream>>>(out, sums, sumsq, gamma, beta);
}

// Round 4
// 128.049 us; speedup vs baseline: 19.5328x; 1.0579x over previous
//
#include <hip/hip_runtime.h>
#include <hip/hip_bf16.h>

#define BB 32
#define CC 128
#define OO 128
#define HH 56
#define WW 56
#define KK 4
#define HW 3136
#define WPLANE 147456
#define EPSV 1e-5f

#define NPOS 348          // 6*58 staged positions
#define PSTR 40           // shorts per position (80 B; 64 B data + 16 B pad)
#define CHUNK_SH (NPOS*PSTR)

typedef __attribute__((ext_vector_type(8))) short short8v;
typedef __attribute__((ext_vector_type(4))) float f32x4;

// ---- convert x -> bf16 channel-last [b][h][w][c], + per-(b,h,c) row sums ----
__global__ void convert_pool_kernel(const float* __restrict__ x,
                                    ushort* __restrict__ xbf,
                                    float* __restrict__ pooledp) {
    const int h = blockIdx.x, b = blockIdx.y;
    __shared__ float xl[128 * 57];
    const float* xp = x + (size_t)(b * CC) * HW + h * WW;
    #pragma unroll
    for (int k = 0; k < 28; ++k) {
        int e = threadIdx.x + k * 256;          // 7168 elems
        int c = e / 56, w = e - c * 56;
        xl[c * 57 + w] = xp[(size_t)c * HW + w];
    }
    __syncthreads();
    ushort* op = xbf + ((size_t)(b * HH + h)) * WW * CC;
    #pragma unroll
    for (int k = 0; k < 7; ++k) {
        int f = threadIdx.x + k * 256;          // 1792 ushort4 units
        int w = f >> 5, c4 = (f & 31) * 4;
        ushort4 v;
        __hip_bfloat16 b0 = __float2bfloat16(xl[(c4 + 0) * 57 + w]);
        __hip_bfloat16 b1 = __float2bfloat16(xl[(c4 + 1) * 57 + w]);
        __hip_bfloat16 b2 = __float2bfloat16(xl[(c4 + 2) * 57 + w]);
        __hip_bfloat16 b3 = __float2bfloat16(xl[(c4 + 3) * 57 + w]);
        v.x = *(ushort*)&b0; v.y = *(ushort*)&b1;
        v.z = *(ushort*)&b2; v.w = *(ushort*)&b3;
        *(ushort4*)(op + (size_t)w * CC + c4) = v;
    }
    if (threadIdx.x < 128) {
        int c = threadIdx.x;
        float s = 0.f;
        #pragma unroll
        for (int w = 0; w < 56; ++w) s += xl[c * 57 + w];
        pooledp[((size_t)(b * HH + h)) * CC + c] = s;
    }
}

// ---- attention: reduce pooled partials + tiny MLP + softmax. block per b ----
__global__ void attn_kernel(const float* __restrict__ pooledp,
                            const float* __restrict__ fc1_w, const float* __restrict__ fc1_b,
                            const float* __restrict__ fc2_w, const float* __restrict__ fc2_b,
                            float* __restrict__ attn) {
    const int b = blockIdx.x, c = threadIdx.x;      // 128 threads
    float s = 0.f;
    for (int h = 0; h < HH; ++h) s += pooledp[((size_t)(b * HH + h)) * CC + c];
    const float pc = s * (1.0f / HW);
    __shared__ float red[8];
    const int lane = c & 63, wid = c >> 6;
    #pragma unroll
    for (int k = 0; k < KK; ++k) {
        float v = pc * fc1_w[k * CC + c];
        for (int off = 32; off > 0; off >>= 1) v += __shfl_down(v, off, 64);
        if (lane == 0) red[k * 2 + wid] = v;
    }
    __syncthreads();
    if (c == 0) {
        float hk[KK], z[KK], m = -1e30f, den = 0.f;
        #pragma unroll
        for (int k = 0; k < KK; ++k)
            hk[k] = fmaxf(red[k * 2] + red[k * 2 + 1] + fc1_b[k], 0.f);
        #pragma unroll
        for (int k = 0; k < KK; ++k) {
            float t = fc2_b[k];
            #pragma unroll
            for (int j = 0; j < KK; ++j) t += hk[j] * fc2_w[k * KK + j];
            z[k] = t; m = fmaxf(m, t);
        }
        #pragma unroll
        for (int k = 0; k < KK; ++k) { z[k] = expf(z[k] - m); den += z[k]; }
        #pragma unroll
        for (int k = 0; k < KK; ++k) attn[b * KK + k] = z[k] / den;
    }
}

// ---- agg_w[b][j][o][c] (bf16) + fused agg_b ----
__global__ void aggw_kernel(const float* __restrict__ attn, const float* __restrict__ weight,
                            const float* __restrict__ bias,
                            ushort* __restrict__ aggw, float* __restrict__ agg_b) {
    int idx = blockIdx.x * 256 + threadIdx.x;
    if (idx < BB * 9 * OO * CC) {
        int c = idx & 127;
        int t = idx >> 7;
        int o = t & 127;
        t >>= 7;
        int j = t % 9;
        int b = t / 9;
        size_t wi = ((size_t)(o * CC + c)) * 9 + j;
        float s = attn[b*KK + 0] * weight[wi]
                + attn[b*KK + 1] * weight[wi + (size_t)WPLANE]
                + attn[b*KK + 2] * weight[wi + (size_t)2*WPLANE]
                + attn[b*KK + 3] * weight[wi + (size_t)3*WPLANE];
        __hip_bfloat16 hb = __float2bfloat16(s);
        aggw[idx] = *(ushort*)&hb;
    }
    if (blockIdx.x < 16) {
        int i = blockIdx.x * 256 + threadIdx.x;   // 0..4095
        int b = i >> 7, o = i & 127;
        float s = 0.f;
        #pragma unroll
        for (int k = 0; k < KK; ++k) s += attn[b*KK + k] * bias[k*OO + o];
        agg_b[i] = s;
    }
}

// ---- implicit-GEMM conv, 8 waves, dbuf LDS, A-prefetch, XCD swizzle ----
__launch_bounds__(512, 4)
__global__ void conv_kernel(const ushort* __restrict__ xbf, const ushort* __restrict__ aggw,
                            const float* __restrict__ agg_b, float* __restrict__ out,
                            float* __restrict__ psum, float* __restrict__ psumsq) {
    // XCD-aware swizzle: 448 blocks, xcd = lid%8 (round-robin dispatch),
    // give each XCD 4 consecutive samples -> aggw L2-resident per XCD.
    const int lid  = blockIdx.x;
    const int gwid = (lid & 7) * 56 + (lid >> 3);
    const int b = gwid / 14;
    const int t = gwid - b * 14;
    const int h0 = t * 4;
    __shared__ ushort xs[2 * CHUNK_SH];  // 55680 B

    const int tid  = threadIdx.x;
    const int lane = tid & 63;
    const int wid  = tid >> 6;
    const int wg = wid & 3;              // o base = wg*32
    const int wy = wid >> 2;             // p base = wy*112
    const int cf = lane & 15;
    const int kg = lane >> 4;

    // staging assignments: units 0..1391 (pos*4 + quad)
    int spos[3]; const ushort* sga[3]; bool lv[3]; bool wv[3];
    #pragma unroll
    for (int u = 0; u < 3; ++u) {
        int un = tid + u * 512;
        wv[u] = un < 1392;
        int pos = un >> 2, quad = un & 3;
        int row = pos / 58, col = pos - row * 58;
        int gh = h0 - 1 + row, gw = col - 1;
        lv[u] = wv[u] && gh >= 0 && gh < HH && gw >= 0 && gw < WW;
        spos[u] = pos * PSTR + quad * 8;
        sga[u] = xbf + ((size_t)((b * HH + gh) * WW + gw)) * CC + quad * 8;
    }

    int bofs[7], oofs[7];
    #pragma unroll
    for (int nf = 0; nf < 7; ++nf) {
        int p = wy * 112 + nf * 16 + cf;
        int r = p / 56, w = p - r * 56;
        bofs[nf] = (((r + 1) * 58 + (w + 1)) * PSTR + kg * 8) * 2;
        oofs[nf] = (h0 + r) * WW + w;
    }

    f32x4 acc[2][7];
    #pragma unroll
    for (int mf = 0; mf < 2; ++mf)
        #pragma unroll
        for (int nf = 0; nf < 7; ++nf) acc[mf][nf] = (f32x4){0.f, 0.f, 0.f, 0.f};

    const ushort* Abase = aggw + (size_t)b * 9 * 16384 + (size_t)(wg * 32 + cf) * 128 + kg * 8;

    const short8v zero8 = (short8v){0,0,0,0,0,0,0,0};
    short8v sreg[3];

    // prologue: x chunk 0 + A j=0
    #pragma unroll
    for (int u = 0; u < 3; ++u) {
        sreg[u] = zero8;
        if (lv[u]) sreg[u] = *(const short8v*)(sga[u]);
    }
    short8v pa0 = *(const short8v*)(Abase);
    short8v pa1 = *(const short8v*)(Abase + 2048);
    #pragma unroll
    for (int u = 0; u < 3; ++u)
        if (wv[u]) *(short8v*)(xs + spos[u]) = sreg[u];

    int cur = 0;
    for (int ci = 0; ci < 4; ++ci) {
        const int c0 = ci * 32;
        if (ci < 3) {
            #pragma unroll
            for (int u = 0; u < 3; ++u) {
                sreg[u] = zero8;
                if (lv[u]) sreg[u] = *(const short8v*)(sga[u] + c0 + 32);
            }
        }
        __syncthreads();
        const ushort* xb = xs + cur * CHUNK_SH;
        #pragma unroll
        for (int j = 0; j < 9; ++j) {
            const int toff = ((j/3 - 1) * 58 + (j%3 - 1)) * (PSTR * 2);
            short8v ca0 = pa0, ca1 = pa1;
            // rolling prefetch: next tap, or next chunk's tap 0
            if (j < 8) {
                pa0 = *(const short8v*)(Abase + (size_t)(j+1) * 16384 + c0);
                pa1 = *(const short8v*)(Abase + (size_t)(j+1) * 16384 + 2048 + c0);
            } else if (ci < 3) {
                pa0 = *(const short8v*)(Abase + c0 + 32);
                pa1 = *(const short8v*)(Abase + 2048 + c0 + 32);
            }
            #pragma unroll
            for (int nf = 0; nf < 7; ++nf) {
                short8v bf = *(const short8v*)((const char*)xb + bofs[nf] + toff);
                acc[0][nf] = __builtin_amdgcn_mfma_f32_16x16x32_bf16(ca0, bf, acc[0][nf], 0, 0, 0);
                acc[1][nf] = __builtin_amdgcn_mfma_f32_16x16x32_bf16(ca1, bf, acc[1][nf], 0, 0, 0);
            }
        }
        if (ci < 3) {
            ushort* xw = xs + (cur ^ 1) * CHUNK_SH;
            #pragma unroll
            for (int u = 0; u < 3; ++u)
                if (wv[u]) *(short8v*)(xw + spos[u]) = sreg[u];
            cur ^= 1;
        }
    }

    // epilogue: bias add, store, fused stats partials
    #pragma unroll
    for (int mf = 0; mf < 2; ++mf) {
        #pragma unroll
        for (int i = 0; i < 4; ++i) {
            const int o = wg * 32 + mf * 16 + kg * 4 + i;
            const float ab = agg_b[b * OO + o];
            float* op = out + ((size_t)(b * OO + o)) * HW;
            float s = 0.f, s2 = 0.f;
            #pragma unroll
            for (int nf = 0; nf < 7; ++nf) {
                float v = acc[mf][nf][i] + ab;
                op[oofs[nf]] = v;
                s += v; s2 += v * v;
            }
            s  += __shfl_xor(s, 1, 64);  s  += __shfl_xor(s, 2, 64);
            s  += __shfl_xor(s, 4, 64);  s  += __shfl_xor(s, 8, 64);
            s2 += __shfl_xor(s2, 1, 64); s2 += __shfl_xor(s2, 2, 64);
            s2 += __shfl_xor(s2, 4, 64); s2 += __shfl_xor(s2, 8, 64);
            if (cf == 0) {
                int row = (b * 14 + t) * 2 + wy;
                psum[row * OO + o]   = s;
                psumsq[row * OO + o] = s2;
            }
        }
    }
}

// ---- final stats: one block per channel ----
__global__ void finstats_kernel(const float* __restrict__ psum, const float* __restrict__ psumsq,
                                float* __restrict__ sums, float* __restrict__ sumsq) {
    const int o = blockIdx.x, l = threadIdx.x;   // 64 threads
    float s = 0.f, s2 = 0.f;
    for (int r = l; r < 896; r += 64) { s += psum[r * OO + o]; s2 += psumsq[r * OO + o]; }
    for (int off = 32; off > 0; off >>= 1) {
        s  += __shfl_down(s, off, 64);
        s2 += __shfl_down(s2, off, 64);
    }
    if (l == 0) { sums[o] = s; sumsq[o] = s2; }
}

// ---- BN + ReLU in place ----
__global__ void bn_kernel(float* __restrict__ out,
                          const float* __restrict__ sums, const float* __restrict__ sumsq,
                          const float* __restrict__ gamma, const float* __restrict__ beta) {
    const float invN = 1.0f / (float)(BB * HW);
    const int total4 = BB * OO * HW / 4;
    for (int i = blockIdx.x * blockDim.x + threadIdx.x; i < total4; i += gridDim.x * blockDim.x) {
        int o = (i / (HW/4)) % OO;
        float mean = sums[o] * invN;
        float var  = sumsq[o] * invN - mean*mean;
        float inv  = rsqrtf(var + EPSV);
        float g  = gamma[o] * inv;
        float bt = beta[o] - mean * g;
        float4 v = ((float4*)out)[i];
        v.x = fmaxf(v.x*g + bt, 0.f);
        v.y = fmaxf(v.y*g + bt, 0.f);
        v.z = fmaxf(v.z*g + bt, 0.f);
        v.w = fmaxf(v.w*g + bt, 0.f);
        ((float4*)out)[i] = v;
    }
}

extern "C" void kernel_launch(void* const* d_in, const int* in_sizes, int n_in,
                              void* d_out, int out_size, void* d_ws, size_t ws_size,
                              hipStream_t stream) {
    const float* x      = (const float*)d_in[0];
    const float* fc1_w  = (const float*)d_in[1];
    const float* fc1_b  = (const float*)d_in[2];
    const float* fc2_w  = (const float*)d_in[3];
    const float* fc2_b  = (const float*)d_in[4];
    const float* weight = (const float*)d_in[5];
    const float* bias   = (const float*)d_in[6];
    const float* gamma  = (const float*)d_in[7];
    const float* beta   = (const float*)d_in[8];
    float* out = (float*)d_out;

    const size_t XBF_ELEMS  = (size_t)BB * HW * CC;        // 12,845,056
    const size_t AGGW_ELEMS = (size_t)BB * 9 * OO * CC;    //  4,718,592
    ushort* xbf  = (ushort*)d_ws;
    ushort* aggw = xbf + XBF_ELEMS;
    float*  wsf  = (float*)(aggw + AGGW_ELEMS);
    float* pooledp = wsf;                    // 229376
    float* attn    = pooledp + 229376;       // 128
    float* agg_b   = attn + 128;             // 4096
    float* psum    = agg_b + 4096;           // 114688
    float* psumsq  = psum + 114688;          // 114688
    float* sums    = psumsq + 114688;        // 128
    float* sumsq   = sums + 128;             // 128

    convert_pool_kernel<<<dim3(HH, BB), 256, 0, stream>>>(x, xbf, pooledp);
    attn_kernel<<<BB, 128, 0, stream>>>(pooledp, fc1_w, fc1_b, fc2_w, fc2_b, attn);
    aggw_kernel<<<(int)((AGGW_ELEMS + 255)/256), 256, 0, stream>>>(attn, weight, bias, aggw, agg_b);
    conv_kernel<<<dim3(448), 512, 0, stream>>>(xbf, aggw, agg_b, out, psum, psumsq);
    finstats_kernel<<<OO, 64, 0, stream>>>(psum, psumsq, sums, sumsq);
    bn_kernel<<<2048, 256, 0, stream>>>(out, sums, sumsq, gamma, beta);
}

// Round 5
// 123.530 us; speedup vs baseline: 20.2474x; 1.0366x over previous
//
#include <hip/hip_runtime.h>
#include <hip/hip_bf16.h>

#define BB 32
#define CC 128
#define OO 128
#define HH 56
#define WW 56
#define KK 4
#define HW 3136
#define WPLANE 147456
#define EPSV 1e-5f

#define NPOS 348          // 6*58 staged positions
#define PSTR 40           // shorts per position (80 B; 64 B data + 16 B pad)
#define CHUNK_SH (NPOS*PSTR)

typedef __attribute__((ext_vector_type(8))) short short8v;
typedef __attribute__((ext_vector_type(4))) float f32x4;

// ---- convert x -> bf16 channel-last [b][h][w][c], + per-(b,h,c) row sums ----
__global__ void convert_pool_kernel(const float* __restrict__ x,
                                    ushort* __restrict__ xbf,
                                    float* __restrict__ pooledp) {
    const int h = blockIdx.x, b = blockIdx.y;
    __shared__ float xl[128 * 57];
    const float* xp = x + (size_t)(b * CC) * HW + h * WW;
    #pragma unroll
    for (int k = 0; k < 28; ++k) {
        int e = threadIdx.x + k * 256;          // 7168 elems
        int c = e / 56, w = e - c * 56;
        xl[c * 57 + w] = xp[(size_t)c * HW + w];
    }
    __syncthreads();
    ushort* op = xbf + ((size_t)(b * HH + h)) * WW * CC;
    #pragma unroll
    for (int k = 0; k < 7; ++k) {
        int f = threadIdx.x + k * 256;          // 1792 ushort4 units
        int w = f >> 5, c4 = (f & 31) * 4;
        ushort4 v;
        __hip_bfloat16 b0 = __float2bfloat16(xl[(c4 + 0) * 57 + w]);
        __hip_bfloat16 b1 = __float2bfloat16(xl[(c4 + 1) * 57 + w]);
        __hip_bfloat16 b2 = __float2bfloat16(xl[(c4 + 2) * 57 + w]);
        __hip_bfloat16 b3 = __float2bfloat16(xl[(c4 + 3) * 57 + w]);
        v.x = *(ushort*)&b0; v.y = *(ushort*)&b1;
        v.z = *(ushort*)&b2; v.w = *(ushort*)&b3;
        *(ushort4*)(op + (size_t)w * CC + c4) = v;
    }
    if (threadIdx.x < 128) {
        int c = threadIdx.x;
        float s = 0.f;
        #pragma unroll
        for (int w = 0; w < 56; ++w) s += xl[c * 57 + w];
        pooledp[((size_t)(b * HH + h)) * CC + c] = s;
    }
}

// ---- attention: reduce pooled partials + tiny MLP + softmax. block per b ----
__global__ void attn_kernel(const float* __restrict__ pooledp,
                            const float* __restrict__ fc1_w, const float* __restrict__ fc1_b,
                            const float* __restrict__ fc2_w, const float* __restrict__ fc2_b,
                            float* __restrict__ attn) {
    const int b = blockIdx.x, c = threadIdx.x;      // 128 threads
    float s = 0.f;
    for (int h = 0; h < HH; ++h) s += pooledp[((size_t)(b * HH + h)) * CC + c];
    const float pc = s * (1.0f / HW);
    __shared__ float red[8];
    const int lane = c & 63, wid = c >> 6;
    #pragma unroll
    for (int k = 0; k < KK; ++k) {
        float v = pc * fc1_w[k * CC + c];
        for (int off = 32; off > 0; off >>= 1) v += __shfl_down(v, off, 64);
        if (lane == 0) red[k * 2 + wid] = v;
    }
    __syncthreads();
    if (c == 0) {
        float hk[KK], z[KK], m = -1e30f, den = 0.f;
        #pragma unroll
        for (int k = 0; k < KK; ++k)
            hk[k] = fmaxf(red[k * 2] + red[k * 2 + 1] + fc1_b[k], 0.f);
        #pragma unroll
        for (int k = 0; k < KK; ++k) {
            float t = fc2_b[k];
            #pragma unroll
            for (int j = 0; j < KK; ++j) t += hk[j] * fc2_w[k * KK + j];
            z[k] = t; m = fmaxf(m, t);
        }
        #pragma unroll
        for (int k = 0; k < KK; ++k) { z[k] = expf(z[k] - m); den += z[k]; }
        #pragma unroll
        for (int k = 0; k < KK; ++k) attn[b * KK + k] = z[k] / den;
    }
}

// ---- agg_w[b][j][o][c] (bf16) + fused agg_b ----
__global__ void aggw_kernel(const float* __restrict__ attn, const float* __restrict__ weight,
                            const float* __restrict__ bias,
                            ushort* __restrict__ aggw, float* __restrict__ agg_b) {
    int idx = blockIdx.x * 256 + threadIdx.x;
    if (idx < BB * 9 * OO * CC) {
        int c = idx & 127;
        int t = idx >> 7;
        int o = t & 127;
        t >>= 7;
        int j = t % 9;
        int b = t / 9;
        size_t wi = ((size_t)(o * CC + c)) * 9 + j;
        float s = attn[b*KK + 0] * weight[wi]
                + attn[b*KK + 1] * weight[wi + (size_t)WPLANE]
                + attn[b*KK + 2] * weight[wi + (size_t)2*WPLANE]
                + attn[b*KK + 3] * weight[wi + (size_t)3*WPLANE];
        __hip_bfloat16 hb = __float2bfloat16(s);
        aggw[idx] = *(ushort*)&hb;
    }
    if (blockIdx.x < 16) {
        int i = blockIdx.x * 256 + threadIdx.x;   // 0..4095
        int b = i >> 7, o = i & 127;
        float s = 0.f;
        #pragma unroll
        for (int k = 0; k < KK; ++k) s += attn[b*KK + k] * bias[k*OO + o];
        agg_b[i] = s;
    }
}

// ---- implicit-GEMM conv: 4 waves, M_wave=64 (4 A-frags per B-read),
//      dbuf LDS, A rolling prefetch, XCD swizzle, fused stats ----
__launch_bounds__(256, 2)
__global__ void conv_kernel(const ushort* __restrict__ xbf, const ushort* __restrict__ aggw,
                            const float* __restrict__ agg_b, float* __restrict__ out,
                            float* __restrict__ psum, float* __restrict__ psumsq) {
    // XCD-aware swizzle: 448 blocks, 4 consecutive samples per XCD.
    const int lid  = blockIdx.x;
    const int gwid = (lid & 7) * 56 + (lid >> 3);
    const int b = gwid / 14;
    const int t = gwid - b * 14;
    const int h0 = t * 4;
    __shared__ ushort xs[2 * CHUNK_SH];  // 55680 B

    const int tid  = threadIdx.x;
    const int lane = tid & 63;
    const int wid  = tid >> 6;
    const int wg = wid & 1;              // o base = wg*64
    const int wy = wid >> 1;             // p base = wy*112
    const int cf = lane & 15;
    const int kg = lane >> 4;

    // staging assignments: units 0..1391 (pos*4 + quad), 6 per thread
    int spos[6]; const ushort* sga[6]; bool lv[6]; bool wv[6];
    #pragma unroll
    for (int u = 0; u < 6; ++u) {
        int un = tid + u * 256;
        wv[u] = un < 1392;
        int pos = un >> 2, quad = un & 3;
        int row = pos / 58, col = pos - row * 58;
        int gh = h0 - 1 + row, gw = col - 1;
        lv[u] = wv[u] && gh >= 0 && gh < HH && gw >= 0 && gw < WW;
        spos[u] = pos * PSTR + quad * 8;
        sga[u] = xbf + ((size_t)((b * HH + gh) * WW + gw)) * CC + quad * 8;
    }

    int bofs[7], oofs[7];
    #pragma unroll
    for (int nf = 0; nf < 7; ++nf) {
        int p = wy * 112 + nf * 16 + cf;
        int r = p / 56, w = p - r * 56;
        bofs[nf] = (((r + 1) * 58 + (w + 1)) * PSTR + kg * 8) * 2;
        oofs[nf] = (h0 + r) * WW + w;
    }

    f32x4 acc[4][7];
    #pragma unroll
    for (int mf = 0; mf < 4; ++mf)
        #pragma unroll
        for (int nf = 0; nf < 7; ++nf) acc[mf][nf] = (f32x4){0.f, 0.f, 0.f, 0.f};

    const ushort* Abase = aggw + (size_t)b * 9 * 16384 + (size_t)(wg * 64 + cf) * 128 + kg * 8;

    const short8v zero8 = (short8v){0,0,0,0,0,0,0,0};
    short8v sreg[6];
    short8v pa[4];

    // prologue: x chunk 0 + A (ci=0, j=0)
    #pragma unroll
    for (int u = 0; u < 6; ++u) {
        sreg[u] = zero8;
        if (lv[u]) sreg[u] = *(const short8v*)(sga[u]);
    }
    #pragma unroll
    for (int mf = 0; mf < 4; ++mf)
        pa[mf] = *(const short8v*)(Abase + mf * 2048);
    #pragma unroll
    for (int u = 0; u < 6; ++u)
        if (wv[u]) *(short8v*)(xs + spos[u]) = sreg[u];

    int cur = 0;
    for (int ci = 0; ci < 4; ++ci) {
        const int c0 = ci * 32;
        if (ci < 3) {
            #pragma unroll
            for (int u = 0; u < 6; ++u) {
                sreg[u] = zero8;
                if (lv[u]) sreg[u] = *(const short8v*)(sga[u] + c0 + 32);
            }
        }
        __syncthreads();
        const ushort* xb = xs + cur * CHUNK_SH;
        #pragma unroll
        for (int j = 0; j < 9; ++j) {
            const int toff = ((j/3 - 1) * 58 + (j%3 - 1)) * (PSTR * 2);
            short8v ca[4];
            #pragma unroll
            for (int mf = 0; mf < 4; ++mf) ca[mf] = pa[mf];
            // rolling prefetch: next tap, or next chunk's tap 0
            if (j < 8) {
                #pragma unroll
                for (int mf = 0; mf < 4; ++mf)
                    pa[mf] = *(const short8v*)(Abase + (size_t)(j+1) * 16384 + mf * 2048 + c0);
            } else if (ci < 3) {
                #pragma unroll
                for (int mf = 0; mf < 4; ++mf)
                    pa[mf] = *(const short8v*)(Abase + mf * 2048 + c0 + 32);
            }
            #pragma unroll
            for (int nf = 0; nf < 7; ++nf) {
                short8v bf = *(const short8v*)((const char*)xb + bofs[nf] + toff);
                #pragma unroll
                for (int mf = 0; mf < 4; ++mf)
                    acc[mf][nf] = __builtin_amdgcn_mfma_f32_16x16x32_bf16(ca[mf], bf, acc[mf][nf], 0, 0, 0);
            }
        }
        if (ci < 3) {
            ushort* xw = xs + (cur ^ 1) * CHUNK_SH;
            #pragma unroll
            for (int u = 0; u < 6; ++u)
                if (wv[u]) *(short8v*)(xw + spos[u]) = sreg[u];
            cur ^= 1;
        }
    }

    // epilogue: bias add, store, fused stats partials
    #pragma unroll
    for (int mf = 0; mf < 4; ++mf) {
        #pragma unroll
        for (int i = 0; i < 4; ++i) {
            const int o = wg * 64 + mf * 16 + kg * 4 + i;
            const float ab = agg_b[b * OO + o];
            float* op = out + ((size_t)(b * OO + o)) * HW;
            float s = 0.f, s2 = 0.f;
            #pragma unroll
            for (int nf = 0; nf < 7; ++nf) {
                float v = acc[mf][nf][i] + ab;
                op[oofs[nf]] = v;
                s += v; s2 += v * v;
            }
            s  += __shfl_xor(s, 1, 64);  s  += __shfl_xor(s, 2, 64);
            s  += __shfl_xor(s, 4, 64);  s  += __shfl_xor(s, 8, 64);
            s2 += __shfl_xor(s2, 1, 64); s2 += __shfl_xor(s2, 2, 64);
            s2 += __shfl_xor(s2, 4, 64); s2 += __shfl_xor(s2, 8, 64);
            if (cf == 0) {
                int row = (b * 14 + t) * 2 + wy;
                psum[row * OO + o]   = s;
                psumsq[row * OO + o] = s2;
            }
        }
    }
}

// ---- final stats: one block per channel ----
__global__ void finstats_kernel(const float* __restrict__ psum, const float* __restrict__ psumsq,
                                float* __restrict__ sums, float* __restrict__ sumsq) {
    const int o = blockIdx.x, l = threadIdx.x;   // 64 threads
    float s = 0.f, s2 = 0.f;
    for (int r = l; r < 896; r += 64) { s += psum[r * OO + o]; s2 += psumsq[r * OO + o]; }
    for (int off = 32; off > 0; off >>= 1) {
        s  += __shfl_down(s, off, 64);
        s2 += __shfl_down(s2, off, 64);
    }
    if (l == 0) { sums[o] = s; sumsq[o] = s2; }
}

// ---- BN + ReLU in place ----
__global__ void bn_kernel(float* __restrict__ out,
                          const float* __restrict__ sums, const float* __restrict__ sumsq,
                          const float* __restrict__ gamma, const float* __restrict__ beta) {
    const float invN = 1.0f / (float)(BB * HW);
    const int total4 = BB * OO * HW / 4;
    for (int i = blockIdx.x * blockDim.x + threadIdx.x; i < total4; i += gridDim.x * blockDim.x) {
        int o = (i / (HW/4)) % OO;
        float mean = sums[o] * invN;
        float var  = sumsq[o] * invN - mean*mean;
        float inv  = rsqrtf(var + EPSV);
        float g  = gamma[o] * inv;
        float bt = beta[o] - mean * g;
        float4 v = ((float4*)out)[i];
        v.x = fmaxf(v.x*g + bt, 0.f);
        v.y = fmaxf(v.y*g + bt, 0.f);
        v.z = fmaxf(v.z*g + bt, 0.f);
        v.w = fmaxf(v.w*g + bt, 0.f);
        ((float4*)out)[i] = v;
    }
}

extern "C" void kernel_launch(void* const* d_in, const int* in_sizes, int n_in,
                              void* d_out, int out_size, void* d_ws, size_t ws_size,
                              hipStream_t stream) {
    const float* x      = (const float*)d_in[0];
    const float* fc1_w  = (const float*)d_in[1];
    const float* fc1_b  = (const float*)d_in[2];
    const float* fc2_w  = (const float*)d_in[3];
    const float* fc2_b  = (const float*)d_in[4];
    const float* weight = (const float*)d_in[5];
    const float* bias   = (const float*)d_in[6];
    const float* gamma  = (const float*)d_in[7];
    const float* beta   = (const float*)d_in[8];
    float* out = (float*)d_out;

    const size_t XBF_ELEMS  = (size_t)BB * HW * CC;        // 12,845,056
    const size_t AGGW_ELEMS = (size_t)BB * 9 * OO * CC;    //  4,718,592
    ushort* xbf  = (ushort*)d_ws;
    ushort* aggw = xbf + XBF_ELEMS;
    float*  wsf  = (float*)(aggw + AGGW_ELEMS);
    float* pooledp = wsf;                    // 229376
    float* attn    = pooledp + 229376;       // 128
    float* agg_b   = attn + 128;             // 4096
    float* psum    = agg_b + 4096;           // 114688
    float* psumsq  = psum + 114688;          // 114688
    float* sums    = psumsq + 114688;        // 128
    float* sumsq   = sums + 128;             // 128

    convert_pool_kernel<<<dim3(HH, BB), 256, 0, stream>>>(x, xbf, pooledp);
    attn_kernel<<<BB, 128, 0, stream>>>(pooledp, fc1_w, fc1_b, fc2_w, fc2_b, attn);
    aggw_kernel<<<(int)((AGGW_ELEMS + 255)/256), 256, 0, stream>>>(attn, weight, bias, aggw, agg_b);
    conv_kernel<<<dim3(448), 256, 0, stream>>>(xbf, aggw, agg_b, out, psum, psumsq);
    finstats_kernel<<<OO, 64, 0, stream>>>(psum, psumsq, sums, sumsq);
    bn_kernel<<<2048, 256, 0, stream>>>(out, sums, sumsq, gamma, beta);
}